// Round 11
// baseline (2353.280 us; speedup 1.0000x reference)
//
#include <hip/hip_runtime.h>

// Att_RNN_GRU: B=128, T=1024, I=128, H=256 (3H=768), A=40
// Phase 1: gx = x @ W_ih^T + b_ih (+b_hh for r,z)  -> f16 [B*T,768]  (MFMA GEMM)
// Phase 2: GRU recurrence, 64 blocks x 2 BATCHES each, 512 thr (8 waves, 2/SIMD,
//          amdgpu_waves_per_eu(2,2) -> full 256-VGPR budget, w[] arch-resident).
//          Thread (g=tid>>1, sub=tid&1) owns rows {g,g+256,g+512}, k-half sub,
//          for BOTH batches (shared W). Independent batch chains interleave ->
//          B's fdot2s hide A's LDS/reduce/trans latency. h in LDS (halves
//          18-uint4 apart, 2-addr broadcast = free); reduce = xor1 DPP
//          butterfly; raw barrier; distance-2 x prefetch; h_t overwrites gx row.
// Phase 3a: s[b,t] = wu . tanh(wv_W @ out + wv_b)   (outs = gx rows, stride 768)
// Phase 3b: softmax over t, context, out = context @ h2o_W^T + b
//
// Workspace: s @0 (512KB), Wp @524288 (384KB), gx @917504 (192MB) = 202.2MB

#define B_ 128
#define T_ 1024
#define I_ 128
#define H_ 256
#define G_ 768
#define A_ 40

typedef _Float16 f16;
typedef _Float16 f16x2 __attribute__((ext_vector_type(2)));
typedef _Float16 f16x8 __attribute__((ext_vector_type(8)));
typedef float    f32x4 __attribute__((ext_vector_type(4)));

__device__ __forceinline__ float fdot2(unsigned a, unsigned b, float c){
#if __has_builtin(__builtin_amdgcn_fdot2)
  return __builtin_amdgcn_fdot2(__builtin_bit_cast(f16x2, a),
                                __builtin_bit_cast(f16x2, b), c, false);
#else
  f16x2 av = __builtin_bit_cast(f16x2, a), bv = __builtin_bit_cast(f16x2, b);
  return c + (float)av.x * (float)bv.x + (float)av.y * (float)bv.y;
#endif
}

__device__ __forceinline__ float2 h2f(unsigned u){
  f16x2 h = __builtin_bit_cast(f16x2, u);
  return make_float2((float)h.x, (float)h.y);
}
__device__ __forceinline__ unsigned f2h2(float a, float b){
  f16x2 h; h.x = (f16)a; h.y = (f16)b;
  return __builtin_bit_cast(unsigned, h);
}
__device__ __forceinline__ float rcp_(float x){ return __builtin_amdgcn_rcpf(x); }
__device__ __forceinline__ float sigm_(float x){ return rcp_(1.f + __expf(-x)); }
__device__ __forceinline__ float tanh_(float x){ return 1.f - 2.f * rcp_(__expf(2.f * x) + 1.f); }

// xor-1 butterfly: both lanes of the (sub=0,sub=1) pair get the pair-sum.
__device__ __forceinline__ float xs(float x){
  int t = __builtin_amdgcn_update_dpp(0, __builtin_bit_cast(int, x),
                                      0xB1, 0xF, 0xF, true);   // quad_perm 1,0,3,2
  return x + __builtin_bit_cast(float, t);
}

// ---------------------------------------------------------------- prep W_hh
// Wp[(c*64+d)*512 + col] = f16 pair of W[c*256 + (col>>1)][(col&1)*128 + 2d .. +1]
// so k_gru thread `tid` loads its 192 w-dwords fully coalesced.
__global__ __launch_bounds__(256) void k_prep_w(const float* __restrict__ W,
                                                unsigned* __restrict__ Wp){
  int idx = blockIdx.x * 256 + threadIdx.x;      // 0 .. 98303
  int dd  = idx >> 9;                            // 0..191 = c*64+d
  int col = idx & 511;                           // k_gru tid
  int c = dd >> 6, d = dd & 63;
  int g = col >> 1, sub = col & 1;
  int r = c * 256 + g;
  int k = sub * 128 + 2 * d;
  Wp[(size_t)dd * 512 + col] = f2h2(W[r * 256 + k], W[r * 256 + k + 1]);
}

// ---------------------------------------------------------------- phase 1
// MFMA GEMM: gx[m][n] = sum_k x[m][k]*W_ih[n][k] + b_ih[n] + (n<512 ? b_hh[n]:0)
__global__ __launch_bounds__(256) void k_gx(const float* __restrict__ x,
                                            const float* __restrict__ wih,
                                            const float* __restrict__ bih,
                                            const float* __restrict__ bhh,
                                            f16* __restrict__ gx){
  __shared__ __align__(16) f16 XA[128 * 128];   // [m][k], byte ^= (m&7)<<4
  __shared__ __align__(16) f16 XB[64 * 128];    // [n][k], same swizzle
  const int tid = threadIdx.x;
  const int m0 = blockIdx.x * 128, n0 = blockIdx.y * 64;

  #pragma unroll
  for (int u = 0; u < 16; ++u){
    int idx = tid + 256 * u;
    int row = idx >> 5, k4 = idx & 31;
    float4 v = *(const float4*)(x + (size_t)(m0 + row) * I_ + k4 * 4);
    unsigned byte = (unsigned)(row * 256 + k4 * 8) ^ ((row & 7) << 4);
    *(uint2*)((char*)XA + byte) = make_uint2(f2h2(v.x, v.y), f2h2(v.z, v.w));
  }
  #pragma unroll
  for (int u = 0; u < 8; ++u){
    int idx = tid + 256 * u;
    int row = idx >> 5, k4 = idx & 31;
    float4 v = *(const float4*)(wih + (size_t)(n0 + row) * I_ + k4 * 4);
    unsigned byte = (unsigned)(row * 256 + k4 * 8) ^ ((row & 7) << 4);
    *(uint2*)((char*)XB + byte) = make_uint2(f2h2(v.x, v.y), f2h2(v.z, v.w));
  }
  __syncthreads();

  const int l = tid & 63, w = tid >> 6;
  const int q = l >> 4, m16 = l & 15;
  f32x4 acc[2][4];
  #pragma unroll
  for (int i = 0; i < 2; ++i)
    #pragma unroll
    for (int nt = 0; nt < 4; ++nt) acc[i][nt] = (f32x4){0.f, 0.f, 0.f, 0.f};

  #pragma unroll
  for (int kt = 0; kt < 4; ++kt){
    f16x8 af[2];
    #pragma unroll
    for (int i = 0; i < 2; ++i){
      int row = (2 * w + i) * 16 + m16;
      unsigned byte = (unsigned)(row * 256 + kt * 64 + q * 16) ^ ((row & 7) << 4);
      af[i] = *(const f16x8*)((const char*)XA + byte);
    }
    #pragma unroll
    for (int nt = 0; nt < 4; ++nt){
      int row = nt * 16 + m16;
      unsigned byte = (unsigned)(row * 256 + kt * 64 + q * 16) ^ ((row & 7) << 4);
      f16x8 bv = *(const f16x8*)((const char*)XB + byte);
      acc[0][nt] = __builtin_amdgcn_mfma_f32_16x16x32_f16(af[0], bv, acc[0][nt], 0, 0, 0);
      acc[1][nt] = __builtin_amdgcn_mfma_f32_16x16x32_f16(af[1], bv, acc[1][nt], 0, 0, 0);
    }
  }

  float bn[4];
  #pragma unroll
  for (int nt = 0; nt < 4; ++nt){
    int n = n0 + nt * 16 + m16;
    bn[nt] = bih[n] + (n < 512 ? bhh[n] : 0.f);
  }

  __syncthreads();
  f16* ST = XA;                                  // reuse as [128][72]
  #pragma unroll
  for (int i = 0; i < 2; ++i)
    #pragma unroll
    for (int nt = 0; nt < 4; ++nt)
      #pragma unroll
      for (int j = 0; j < 4; ++j){
        int row = (2 * w + i) * 16 + 4 * q + j;
        ST[row * 72 + nt * 16 + m16] = (f16)(acc[i][nt][j] + bn[nt]);
      }
  __syncthreads();
  #pragma unroll
  for (int u = 0; u < 4; ++u){
    int idx = tid + 256 * u;
    int row = idx >> 3, c = idx & 7;
    uint4 v = *(const uint4*)(ST + row * 72 + c * 8);
    *(uint4*)(gx + (size_t)(m0 + row) * G_ + n0 + c * 8) = v;
  }
}

// ---------------------------------------------------------------- phase 2
// 64 blocks x 512 threads (8 waves, EXACTLY 2/SIMD); 2 batches share w[].
__global__ __launch_bounds__(512)
__attribute__((amdgpu_waves_per_eu(2, 2)))
void k_gru(const unsigned* __restrict__ Wp,
           unsigned* __restrict__ gx,
           const float* __restrict__ bhh){
  __shared__ uint4 hb[2][2][36];  // [buf][batch][half0 @0..15, half1 @18..33]
  const int tid = threadIdx.x;
  const int g = tid >> 1, sub = tid & 1;
  const int b0 = blockIdx.x * 2;

  unsigned w0[64], w1[64], w2[64];
  #pragma unroll
  for (int d = 0; d < 64; ++d) w0[d] = Wp[(size_t)(d      ) * 512 + tid];
  #pragma unroll
  for (int d = 0; d < 64; ++d) w1[d] = Wp[(size_t)(64  + d) * 512 + tid];
  #pragma unroll
  for (int d = 0; d < 64; ++d) w2[d] = Wp[(size_t)(128 + d) * 512 + tid];

  const float bn_ = bhh[512 + g];
  float hpA = 0.f, hpB = 0.f;
  if (tid < 72) ((uint4*)hb)[tid] = make_uint4(0, 0, 0, 0);   // buf0, both batches

  f16* gxA = (f16*)gx + (size_t)(b0    ) * T_ * G_;
  f16* gxB = (f16*)gx + (size_t)(b0 + 1) * T_ * G_;

  // distance-2 x pipelines, both batches, ALL lanes (gates are redundant)
  f16 ar0 = gxA[g],      az0 = gxA[H_+g],      an0 = gxA[2*H_+g];
  f16 ar1 = gxA[G_+g],   az1 = gxA[G_+H_+g],   an1 = gxA[G_+2*H_+g];
  f16 br0 = gxB[g],      bz0 = gxB[H_+g],      bn0 = gxB[2*H_+g];
  f16 br1 = gxB[G_+g],   bz1 = gxB[G_+H_+g],   bn1 = gxB[G_+2*H_+g];
  __syncthreads();

  int cur = 0;
  for (int t = 0; t < T_; ++t){
    // prefetch t+2 (wrapped; garbage never consumed)
    const f16* nxA = gxA + (size_t)((t + 2) & (T_ - 1)) * G_;
    const f16* nxB = gxB + (size_t)((t + 2) & (T_ - 1)) * G_;
    f16 ar2 = nxA[g], az2 = nxA[H_+g], an2 = nxA[2*H_+g];
    f16 br2 = nxB[g], bz2 = nxB[H_+g], bn2 = nxB[2*H_+g];

    const uint4* hA = &hb[cur][0][sub * 18];
    const uint4* hB = &hb[cur][1][sub * 18];
    float aA0=0,bA0=0,aA1=0,bA1=0,aA2=0,bA2=0;
    float aB0=0,bB0=0,aB1=0,bB1=0,aB2=0,bB2=0;
    #pragma unroll
    for (int i = 0; i < 16; ++i){
      uint4 hvA = hA[i];
      uint4 hvB = hB[i];
      aA0=fdot2(w0[4*i+0],hvA.x,aA0); bA0=fdot2(w0[4*i+1],hvA.y,bA0);
      aA0=fdot2(w0[4*i+2],hvA.z,aA0); bA0=fdot2(w0[4*i+3],hvA.w,bA0);
      aB0=fdot2(w0[4*i+0],hvB.x,aB0); bB0=fdot2(w0[4*i+1],hvB.y,bB0);
      aB0=fdot2(w0[4*i+2],hvB.z,aB0); bB0=fdot2(w0[4*i+3],hvB.w,bB0);
      aA1=fdot2(w1[4*i+0],hvA.x,aA1); bA1=fdot2(w1[4*i+1],hvA.y,bA1);
      aA1=fdot2(w1[4*i+2],hvA.z,aA1); bA1=fdot2(w1[4*i+3],hvA.w,bA1);
      aB1=fdot2(w1[4*i+0],hvB.x,aB1); bB1=fdot2(w1[4*i+1],hvB.y,bB1);
      aB1=fdot2(w1[4*i+2],hvB.z,aB1); bB1=fdot2(w1[4*i+3],hvB.w,bB1);
      aA2=fdot2(w2[4*i+0],hvA.x,aA2); bA2=fdot2(w2[4*i+1],hvA.y,bA2);
      aA2=fdot2(w2[4*i+2],hvA.z,aA2); bA2=fdot2(w2[4*i+3],hvA.w,bA2);
      aB2=fdot2(w2[4*i+0],hvB.x,aB2); bB2=fdot2(w2[4*i+1],hvB.y,bB2);
      aB2=fdot2(w2[4*i+2],hvB.z,aB2); bB2=fdot2(w2[4*i+3],hvB.w,bB2);
    }
    float sAr = xs(aA0 + bA0), sAz = xs(aA1 + bA1), sAn = xs(aA2 + bA2);
    float sBr = xs(aB0 + bB0), sBz = xs(aB1 + bB1), sBn = xs(aB2 + bB2);

    // gates: both sub-lanes compute (redundant, no divergence); two
    // independent chains (A,B) overlap on the trans pipe.
    float rA = sigm_((float)ar0 + sAr);
    float zA = sigm_((float)az0 + sAz);
    float nA = tanh_((float)an0 + rA * (sAn + bn_));
    float hAv = (1.f - zA) * nA + zA * hpA;  hpA = hAv;
    float rB = sigm_((float)br0 + sBr);
    float zB = sigm_((float)bz0 + sBz);
    float nB = tanh_((float)bn0 + rB * (sBn + bn_));
    float hBv = (1.f - zB) * nB + zB * hpB;  hpB = hBv;

    if (sub == 0){
      f16 ha = (f16)hAv, hbv = (f16)hBv;
      ((f16*)&hb[cur ^ 1][0][0])[g + (g >> 7) * 16] = ha;
      ((f16*)&hb[cur ^ 1][1][0])[g + (g >> 7) * 16] = hbv;
      gxA[(size_t)t * G_ + g] = ha;              // stores stay in flight
      gxB[(size_t)t * G_ + g] = hbv;
    }
    ar0 = ar1; az0 = az1; an0 = an1;  ar1 = ar2; az1 = az2; an1 = an2;
    br0 = br1; bz0 = bz1; bn0 = bn1;  br1 = br2; bz1 = bz2; bn1 = bn2;

    // raw barrier: commit LDS writes; vmcnt not drained
    asm volatile("s_waitcnt lgkmcnt(0)" ::: "memory");
    __builtin_amdgcn_s_barrier();
    asm volatile("" ::: "memory");
    cur ^= 1;
  }
}

// ---------------------------------------------------------------- phase 3a
__global__ __launch_bounds__(256) void k_score(const f16* __restrict__ outs,
                                               const float* __restrict__ wvW,
                                               const float* __restrict__ wvb,
                                               const float* __restrict__ wu,
                                               float* __restrict__ s){
  __shared__ uint4 OT[32 * 33];
  __shared__ float WV[A_ * 260];
  const int tid = threadIdx.x;
  const int m0 = blockIdx.x * 32;

  #pragma unroll
  for (int u = 0; u < 4; ++u){
    int idx = tid + 256 * u;
    int row = idx >> 5, col = idx & 31;
    OT[row * 33 + col] = *(const uint4*)(outs + (size_t)(m0 + row) * G_ + col * 8);
  }
  #pragma unroll
  for (int u = 0; u < 10; ++u){
    int f = tid + 256 * u;
    int a = f >> 6, k4 = f & 63;
    float4 v = *(const float4*)(wvW + a * 256 + k4 * 4);
    *(float4*)(WV + a * 260 + k4 * 4) = v;
  }
  __syncthreads();

  const int m = tid >> 3, aq = tid & 7;
  float acc[5] = {0.f, 0.f, 0.f, 0.f, 0.f};
  for (int i = 0; i < 32; ++i){
    uint4 oc = OT[m * 33 + i];
    float2 o01 = h2f(oc.x), o23 = h2f(oc.y), o45 = h2f(oc.z), o67 = h2f(oc.w);
    #pragma unroll
    for (int sa = 0; sa < 5; ++sa){
      int a = aq + sa * 8;
      const float* wr = &WV[a * 260 + i * 8];
      float4 w0 = *(const float4*)wr;
      float4 w1 = *(const float4*)(wr + 4);
      acc[sa] += o01.x*w0.x + o01.y*w0.y + o23.x*w0.z + o23.y*w0.w
               + o45.x*w1.x + o45.y*w1.y + o67.x*w1.z + o67.y*w1.w;
    }
  }
  float sp = 0.f;
  #pragma unroll
  for (int sa = 0; sa < 5; ++sa){
    int a = aq + sa * 8;
    sp += wu[a] * tanh_(acc[sa] + wvb[a]);
  }
  sp += __shfl_xor(sp, 1);
  sp += __shfl_xor(sp, 2);
  sp += __shfl_xor(sp, 4);
  if (aq == 0) s[m0 + m] = sp;
}

// ---------------------------------------------------------------- phase 3b
__global__ __launch_bounds__(256) void k_ctx(const f16* __restrict__ outs,
                                             const float* __restrict__ s,
                                             const float* __restrict__ h2oW,
                                             const float* __restrict__ h2ob,
                                             float* __restrict__ out){
  __shared__ float AL[T_];
  __shared__ float red[8];
  const int tid = threadIdx.x;
  const int b = blockIdx.x;
  const float* sb = s + (size_t)b * T_;

  float v0 = sb[tid], v1 = sb[tid + 256], v2 = sb[tid + 512], v3 = sb[tid + 768];
  float mx = fmaxf(fmaxf(v0, v1), fmaxf(v2, v3));
  #pragma unroll
  for (int msk = 1; msk < 64; msk <<= 1) mx = fmaxf(mx, __shfl_xor(mx, msk));
  if ((tid & 63) == 0) red[tid >> 6] = mx;
  __syncthreads();
  mx = fmaxf(fmaxf(red[0], red[1]), fmaxf(red[2], red[3]));

  float e0 = __expf(v0 - mx), e1 = __expf(v1 - mx), e2 = __expf(v2 - mx), e3 = __expf(v3 - mx);
  float zs = e0 + e1 + e2 + e3;
  #pragma unroll
  for (int msk = 1; msk < 64; msk <<= 1) zs += __shfl_xor(zs, msk);
  if ((tid & 63) == 0) red[4 + (tid >> 6)] = zs;
  __syncthreads();
  float invZ = 1.f / (red[4] + red[5] + red[6] + red[7]);
  AL[tid] = e0 * invZ; AL[tid + 256] = e1 * invZ;
  AL[tid + 512] = e2 * invZ; AL[tid + 768] = e3 * invZ;
  __syncthreads();

  const f16* ob = outs + (size_t)b * T_ * G_;
  float acc = 0.f;
  for (int t = 0; t < T_; t += 4){
    acc += AL[t + 0] * (float)ob[(size_t)(t + 0) * G_ + tid];
    acc += AL[t + 1] * (float)ob[(size_t)(t + 1) * G_ + tid];
    acc += AL[t + 2] * (float)ob[(size_t)(t + 2) * G_ + tid];
    acc += AL[t + 3] * (float)ob[(size_t)(t + 3) * G_ + tid];
  }
  __syncthreads();
  float val = acc * h2oW[tid];
  #pragma unroll
  for (int msk = 1; msk < 64; msk <<= 1) val += __shfl_xor(val, msk);
  if ((tid & 63) == 0) red[tid >> 6] = val;
  __syncthreads();
  if (tid == 0) out[b] = red[0] + red[1] + red[2] + red[3] + h2ob[0];
}

// ---------------------------------------------------------------- launch
extern "C" void kernel_launch(void* const* d_in, const int* in_sizes, int n_in,
                              void* d_out, int out_size, void* d_ws, size_t ws_size,
                              hipStream_t stream){
  const float* x    = (const float*)d_in[0];
  const float* wih  = (const float*)d_in[1];
  const float* whh  = (const float*)d_in[2];
  const float* bih  = (const float*)d_in[3];
  const float* bhh  = (const float*)d_in[4];
  const float* wvW  = (const float*)d_in[5];
  const float* wvb  = (const float*)d_in[6];
  const float* wu   = (const float*)d_in[7];
  const float* h2oW = (const float*)d_in[8];
  const float* h2ob = (const float*)d_in[9];
  float* out = (float*)d_out;

  char* ws = (char*)d_ws;
  float*    s  = (float*)ws;                      //     524,288 B
  unsigned* Wp = (unsigned*)(ws + 524288);        //     393,216 B
  unsigned* gx = (unsigned*)(ws + 917504);        // 201,326,592 B

  k_prep_w<<<384, 256, 0, stream>>>(whh, Wp);
  k_gx<<<dim3((B_ * T_) / 128, G_ / 64), 256, 0, stream>>>(x, wih, bih, bhh, (f16*)gx);
  k_gru<<<B_ / 2, 512, 0, stream>>>(Wp, gx, bhh);
  k_score<<<(B_ * T_) / 32, 256, 0, stream>>>((const f16*)gx, wvW, wvb, wu, s);
  k_ctx<<<B_, 256, 0, stream>>>((const f16*)gx, s, h2oW, h2ob, out);
}